// Round 2
// baseline (1249.274 us; speedup 1.0000x reference)
//
#include <hip/hip_runtime.h>
#include <hip/hip_bf16.h>

#define Dd 1024
#define Bb 8192

typedef unsigned short u16;
typedef __attribute__((ext_vector_type(8))) short short8;
typedef __attribute__((ext_vector_type(4))) float f32x4;

static constexpr size_t DD  = (size_t)Dd * Dd;   // 1M
static constexpr size_t BD  = (size_t)Bb * Dd;   // 8M
static constexpr size_t MBy = 1ull << 20;

__device__ __forceinline__ float bf2f(u16 v) {
  union { unsigned u; float f; } c; c.u = ((unsigned)v) << 16; return c.f;
}
__device__ __forceinline__ u16 f2bf(float f) {
  union { float f; unsigned u; } c; c.f = f;
  return (u16)((c.u + 0x7fffu + ((c.u >> 16) & 1u)) >> 16);
}

// ---------------- NT GEMM: C[m][n] = alpha * sum_k A[m][k]*Bt[n][k] (+beta*C) ----------
// A: M x K row-major bf16 (hi [+lo]) ; Bt: N x K row-major bf16 (hi [+lo]) ; C: f32 or bf16
struct ZP { const u16* Ah; const u16* Al; const u16* Bh; const u16* Bl; void* C; float alpha; float beta; };
struct GArgs { ZP z[8]; int K, lda, ldb; long ldc; int cstride; };

template<bool SPLIT, bool OBF>
__global__ __launch_bounds__(256) void gemm_nt(GArgs a) {
  __shared__ __align__(16) u16 smem[SPLIT ? 32768 : 16384];
  u16* As = smem;
  u16* Bs = smem + 8192;
  const ZP p = a.z[blockIdx.z];
  const int tid  = threadIdx.x;
  const int lane = tid & 63, wv = tid >> 6;
  const long brow = (long)blockIdx.y * 128, bcol = (long)blockIdx.x * 128;
  const int wm = (wv & 1) * 64, wn = (wv >> 1) * 64;
  const int srow = wv * 8 + (lane >> 3);
  const int scol = (lane & 7) * 8;
  f32x4 acc[4][4];
#pragma unroll
  for (int i = 0; i < 4; ++i)
#pragma unroll
    for (int j = 0; j < 4; ++j) { f32x4 zv = {0.f, 0.f, 0.f, 0.f}; acc[i][j] = zv; }

  for (int kt = 0; kt < a.K; kt += 64) {
    __syncthreads();
#pragma unroll
    for (int i = 0; i < 4; ++i) {
      const int rr = i * 32 + srow;
      const int lb = (i * 32 + wv * 8) * 64;
      const u16* ga = p.Ah + (brow + rr) * (long)a.lda + kt + scol;
      const u16* gb = p.Bh + (bcol + rr) * (long)a.ldb + kt + scol;
      __builtin_amdgcn_global_load_lds((const __attribute__((address_space(1))) void*)ga,
                                       (__attribute__((address_space(3))) void*)(As + lb), 16, 0, 0);
      __builtin_amdgcn_global_load_lds((const __attribute__((address_space(1))) void*)gb,
                                       (__attribute__((address_space(3))) void*)(Bs + lb), 16, 0, 0);
      if constexpr (SPLIT) {
        const u16* ga2 = p.Al + (brow + rr) * (long)a.lda + kt + scol;
        const u16* gb2 = p.Bl + (bcol + rr) * (long)a.ldb + kt + scol;
        __builtin_amdgcn_global_load_lds((const __attribute__((address_space(1))) void*)ga2,
                                         (__attribute__((address_space(3))) void*)(smem + 16384 + lb), 16, 0, 0);
        __builtin_amdgcn_global_load_lds((const __attribute__((address_space(1))) void*)gb2,
                                         (__attribute__((address_space(3))) void*)(smem + 24576 + lb), 16, 0, 0);
      }
    }
    __syncthreads();
#pragma unroll
    for (int kk = 0; kk < 64; kk += 32) {
      const int ko = kk + ((lane >> 4) * 8);
      short8 af[4], bfv[4], al[4], bl[4];
#pragma unroll
      for (int i = 0; i < 4; ++i) {
        af[i]  = *(const short8*)(As + (wm + i * 16 + (lane & 15)) * 64 + ko);
        bfv[i] = *(const short8*)(Bs + (wn + i * 16 + (lane & 15)) * 64 + ko);
        if constexpr (SPLIT) {
          al[i] = *(const short8*)(smem + 16384 + (wm + i * 16 + (lane & 15)) * 64 + ko);
          bl[i] = *(const short8*)(smem + 24576 + (wn + i * 16 + (lane & 15)) * 64 + ko);
        }
      }
#pragma unroll
      for (int i = 0; i < 4; ++i)
#pragma unroll
        for (int j = 0; j < 4; ++j) {
          acc[i][j] = __builtin_amdgcn_mfma_f32_16x16x32_bf16(af[i], bfv[j], acc[i][j], 0, 0, 0);
          if constexpr (SPLIT) {
            acc[i][j] = __builtin_amdgcn_mfma_f32_16x16x32_bf16(al[i], bfv[j], acc[i][j], 0, 0, 0);
            acc[i][j] = __builtin_amdgcn_mfma_f32_16x16x32_bf16(af[i], bl[j], acc[i][j], 0, 0, 0);
          }
        }
    }
  }
  const long crow = brow + wm + ((lane >> 4) * 4);
  const long ccol = bcol + wn + (lane & 15);
#pragma unroll
  for (int i = 0; i < 4; ++i)
#pragma unroll
    for (int j = 0; j < 4; ++j)
#pragma unroll
      for (int r = 0; r < 4; ++r) {
        const long cidx = (crow + i * 16 + r) * a.ldc + (ccol + j * 16) * (long)a.cstride;
        float v = acc[i][j][r] * p.alpha;
        if constexpr (OBF) {
          ((u16*)p.C)[cidx] = f2bf(v);
        } else {
          float* C = (float*)p.C;
          if (p.beta != 0.0f) v += p.beta * C[cidx];
          C[cidx] = v;
        }
      }
}

// ---------------- elementwise kernels ----------------
// planes layout for complex d x d sets: [y*2*DD + 0] = re, [y*2*DD + DD] = im, y in {0(u),1(v)}

__global__ void k_buildA(const float* ur, const float* ui, const float* vr, const float* vi,
                         float* Af32, u16* Ahi, u16* Alo) {
  const int y = blockIdx.y;
  const size_t idx = (size_t)blockIdx.x * 256 + threadIdx.x;
  const size_t r = idx >> 10, c = idx & 1023;
  const float* re = y ? vr : ur; const float* im = y ? vi : ui;
  float are = 0.5f * (re[idx] - re[c * Dd + r]);
  float aim = 0.5f * (im[idx] + im[c * Dd + r]);
  size_t pr = (size_t)y * 2 * DD + idx, pi = pr + DD;
  Af32[pr] = are; Af32[pi] = aim;
  u16 h = f2bf(are); Ahi[pr] = h; Alo[pr] = f2bf(are - bf2f(h));
  h = f2bf(aim); Ahi[pi] = h; Alo[pi] = f2bf(aim - bf2f(h));
}

// X0 = I + A + A^2 ;  A^2: re = -T0-T1, im = T2-T3 (skew-Hermitian Bt trick)
__global__ void k_x0(const float* Af32, const float* T, float* Xf32, u16* Xhi, u16* XThi) {
  const int y = blockIdx.y;
  const size_t idx = (size_t)blockIdx.x * 256 + threadIdx.x;
  const size_t r = idx >> 10, c = idx & 1023;
  const size_t t0 = (size_t)y * 4 * DD + idx;
  float a2re = -T[t0] - T[t0 + DD];
  float a2im =  T[t0 + 2 * DD] - T[t0 + 3 * DD];
  size_t pr = (size_t)y * 2 * DD + idx, pi = pr + DD;
  float xre = Af32[pr] + a2re + (r == c ? 1.0f : 0.0f);
  float xim = Af32[pi] + a2im;
  Xf32[pr] = xre; Xf32[pi] = xim;
  Xhi[pr] = f2bf(xre); Xhi[pi] = f2bf(xim);
  size_t tr = c * Dd + r;
  size_t qr = (size_t)y * 2 * DD + tr;
  XThi[qr] = f2bf(xre); XThi[qr + DD] = f2bf(xim);
}

// Wt[n][k] = (2I - X + Q)[k][n] ; Q: re = T0-T1, im = T2+T3
__global__ void k_wt(const float* Xf32, const float* T, u16* WThi, u16* WTlo) {
  const int y = blockIdx.y;
  const size_t idx = (size_t)blockIdx.x * 256 + threadIdx.x;  // write index: n*Dd + k
  const size_t n = idx >> 10, k = idx & 1023;
  const size_t ridx = k * Dd + n;
  const size_t t0 = (size_t)y * 4 * DD;
  float qre = T[t0 + ridx] - T[t0 + DD + ridx];
  float qim = T[t0 + 2 * DD + ridx] + T[t0 + 3 * DD + ridx];
  size_t pr = (size_t)y * 2 * DD, pi = pr + DD;
  float wre = (n == k ? 2.0f : 0.0f) - Xf32[pr + ridx] + qre;
  float wim = -Xf32[pi + ridx] + qim;
  u16 h = f2bf(wre); WThi[pr + idx] = h;
  if (WTlo) WTlo[pr + idx] = f2bf(wre - bf2f(h));
  h = f2bf(wim); WThi[pi + idx] = h;
  if (WTlo) WTlo[pi + idx] = f2bf(wim - bf2f(h));
}

// X' = X@W : re = T0-T1, im = T2+T3 ; optionally emit hi/lo splits (pre-refinement)
__global__ void k_xn(const float* T, float* Xf32, u16* Xhi, u16* XThi, u16* Xlo, u16* XTlo) {
  const int y = blockIdx.y;
  const size_t idx = (size_t)blockIdx.x * 256 + threadIdx.x;
  const size_t r = idx >> 10, c = idx & 1023;
  const size_t t0 = (size_t)y * 4 * DD + idx;
  float xre = T[t0] - T[t0 + DD];
  float xim = T[t0 + 2 * DD] + T[t0 + 3 * DD];
  size_t pr = (size_t)y * 2 * DD + idx, pi = pr + DD;
  Xf32[pr] = xre; Xf32[pi] = xim;
  u16 hr = f2bf(xre), hi_ = f2bf(xim);
  Xhi[pr] = hr; Xhi[pi] = hi_;
  size_t tr = (size_t)y * 2 * DD + c * Dd + r;
  XThi[tr] = hr; XThi[tr + DD] = hi_;
  if (Xlo) {
    u16 lr = f2bf(xre - bf2f(hr)), li = f2bf(xim - bf2f(hi_));
    Xlo[pr] = lr; Xlo[pi] = li;
    XTlo[tr] = lr; XTlo[tr + DD] = li;
  }
}

// From refined T (X@W): Cay = 2X-I ; emit GEMM operands for M / M_inv
__global__ void k_finalUV(const float* T, const float* logsig,
                          u16* VsHi, u16* VsLo, u16* UHi, u16* ULo, u16* UsHi, u16* VHi) {
  const int y = blockIdx.y;
  const size_t idx = (size_t)blockIdx.x * 256 + threadIdx.x;
  const size_t r = idx >> 10, c = idx & 1023;
  const size_t t0 = (size_t)y * 4 * DD + idx;
  float xre = 2.0f * (T[t0] - T[t0 + DD]) - (r == c ? 1.0f : 0.0f);
  float xim = 2.0f * (T[t0 + 2 * DD] + T[t0 + 3 * DD]);
  if (y == 0) {  // U:  hi/lo (Bt of M_inv) ; U*s hi (A of M)
    float s = expf(logsig[c]);
    u16 h = f2bf(xre); UHi[idx] = h; ULo[idx] = f2bf(xre - bf2f(h));
    h = f2bf(xim); UHi[DD + idx] = h; ULo[DD + idx] = f2bf(xim - bf2f(h));
    UsHi[idx] = f2bf(xre * s); UsHi[DD + idx] = f2bf(xim * s);
  } else {       // V:  hi (Bt of M) ; V*s_inv hi/lo (A of M_inv)
    float si = expf(-logsig[c]);
    VHi[idx] = f2bf(xre); VHi[DD + idx] = f2bf(xim);
    float a = xre * si, b = xim * si;
    u16 h = f2bf(a); VsHi[idx] = h; VsLo[idx] = f2bf(a - bf2f(h));
    h = f2bf(b); VsHi[DD + idx] = h; VsLo[DD + idx] = f2bf(b - bf2f(h));
  }
}

// M_inv = T0+T1, T2-T3 ; M = T4+T5, T6-T7 ; also transposed hi/lo of M_inv for G
__global__ void k_cmb_M(const float* T, u16* MiRe, u16* MiIm, u16* MiT, u16* MRe, u16* MIm) {
  const size_t idx = (size_t)blockIdx.x * 256 + threadIdx.x;
  const size_t r = idx >> 10, c = idx & 1023;
  float mire = T[idx] + T[DD + idx];
  float miim = T[2 * DD + idx] - T[3 * DD + idx];
  float mre  = T[4 * DD + idx] + T[5 * DD + idx];
  float mim  = T[6 * DD + idx] - T[7 * DD + idx];
  MiRe[idx] = f2bf(mire); MiIm[idx] = f2bf(miim);
  MRe[idx]  = f2bf(mre);  MIm[idx]  = f2bf(mim);
  size_t tr = c * Dd + r;
  u16 h = f2bf(mire); MiT[tr] = h;          MiT[2 * DD + tr] = f2bf(mire - bf2f(h));
  h = f2bf(miim);     MiT[DD + tr] = h;     MiT[3 * DD + tr] = f2bf(miim - bf2f(h));
}

__global__ void k_split(const float* src, u16* hi, u16* lo, size_t n) {
  const size_t idx = (size_t)blockIdx.x * 256 + threadIdx.x;
  if (idx >= n) return;
  float v = src[idx]; u16 h = f2bf(v); hi[idx] = h;
  if (lo) lo[idx] = f2bf(v - bf2f(h));
}

__global__ void k_pointwise(const u16* HtRe, const u16* HtIm, const u16* XtRe, const u16* XtIm,
                            const float* delta, const float* dt, const float* ld, const float* lf,
                            const float* dts, const float* sre, const float* sim,
                            const float* lwre, const float* lwim, const float* selb,
                            u16* HnRe, u16* HnIm) {
  const size_t idx = (size_t)blockIdx.x * 256 + threadIdx.x;  // < BD
  const int b = (int)(idx >> 10); const int c = (int)(idx & 1023);
  float dre = delta[(size_t)b * 2048 + c] + selb[c];
  float dim = delta[(size_t)b * 2048 + 1024 + c] + selb[1024 + c];
  float lamre = -expf(ld[c]) + lwre[c] + dre;
  float lamim = lf[c] + lwim[c] + dim;
  float dtv = dt[b];
  float dtn = dtv / dts[c];
  float zre = lamre * dtn, zim = lamim * dtn;
  float r2 = zre * zre + zim * zim;
  float er = expf(zre); float sn, cs; __sincosf(zim, &sn, &cs);
  float dcre = er * cs, dcim = er * sn;
  float p1re, p1im;
  if (r2 < 1e-8f) {
    p1re = 1.0f + 0.5f * zre + (zre * zre - zim * zim) * (1.0f / 6.0f);
    p1im = 0.5f * zim + (zre * zim) * (1.0f / 3.0f);
  } else {
    float inv = 1.0f / r2;
    float nre = dcre - 1.0f, nim = dcim;
    p1re = (nre * zre + nim * zim) * inv;
    p1im = (nim * zre - nre * zim) * inv;
  }
  float fre = p1re * dtv, fim = p1im * dtv;  // phi1 * dt
  float hre = bf2f(HtRe[idx]), him = bf2f(HtIm[idx]);
  float xre = bf2f(XtRe[idx]) + sre[c], xim = bf2f(XtIm[idx]) + sim[c];
  float ore = hre * dcre - him * dcim + xre * fre - xim * fim;
  float oim = hre * dcim + him * dcre + xre * fim + xim * fre;
  HnRe[idx] = f2bf(ore); HnIm[idx] = f2bf(oim);
}

__global__ void k_fill(float* p, size_t n, float v) {
  const size_t idx = (size_t)blockIdx.x * 256 + threadIdx.x;
  if (idx < n) p[idx] = v;
}

// ---------------- host ----------------
static void launch_gemm(bool split, bool obf, int M, int N, int K, int lda, int ldb,
                        long ldc, int cstride, int nz, const ZP* z, hipStream_t s) {
  GArgs a; a.K = K; a.lda = lda; a.ldb = ldb; a.ldc = ldc; a.cstride = cstride;
  for (int i = 0; i < 8; ++i) a.z[i] = z[i < nz ? i : 0];
  dim3 g(N / 128, M / 128, nz), blk(256);
  if (split)      gemm_nt<true,  false><<<g, blk, 0, s>>>(a);
  else if (obf)   gemm_nt<false, true ><<<g, blk, 0, s>>>(a);
  else            gemm_nt<false, false><<<g, blk, 0, s>>>(a);
}

extern "C" void kernel_launch(void* const* d_in, const int* in_sizes, int n_in,
                              void* d_out, int out_size, void* d_ws, size_t ws_size,
                              hipStream_t stream) {
  const float* h_prev  = (const float*)d_in[0];
  const float* x_input = (const float*)d_in[1];
  const float* dt      = (const float*)d_in[2];
  const float* ur      = (const float*)d_in[3];
  const float* ui      = (const float*)d_in[4];
  const float* vr      = (const float*)d_in[5];
  const float* vi      = (const float*)d_in[6];
  const float* logsig  = (const float*)d_in[7];
  const float* ld      = (const float*)d_in[8];
  const float* lf      = (const float*)d_in[9];
  const float* dts     = (const float*)d_in[10];
  const float* sre     = (const float*)d_in[11];
  const float* sim     = (const float*)d_in[12];
  const float* lwre    = (const float*)d_in[13];
  const float* lwim    = (const float*)d_in[14];
  const float* sel_w   = (const float*)d_in[15];
  const float* sel_b   = (const float*)d_in[16];
  float* out = (float*)d_out;
  char* ws = (char*)d_ws;

  // out_size == BD       -> harness flattened complex ref to float32 (real part only)
  // out_size == 2*BD     -> interleaved complex (re,im) pairs
  const bool realOnly = ((size_t)out_size == BD);
  const bool interleaved = ((size_t)out_size == 2 * BD);
  if ((!realOnly && !interleaved) || ws_size < 224 * MBy) {
    // diagnostic signature: absmax ~1e9 means unexpected out_size / ws too small
    k_fill<<<dim3(((size_t)out_size + 255) / 256), dim3(256), 0, stream>>>(out, (size_t)out_size, 1e9f);
    return;
  }

  // persistent region [0,16MB)
  u16* MiRe_b = (u16*)(ws + 0 * MBy);
  u16* MiIm_b = (u16*)(ws + 2 * MBy);
  u16* MRe_b  = (u16*)(ws + 4 * MBy);
  u16* MIm_b  = (u16*)(ws + 6 * MBy);
  u16* G_hi   = (u16*)(ws + 8 * MBy);
  u16* G_lo   = (u16*)(ws + 12 * MBy);
  char* AR = ws + 16 * MBy;  // arena (phase A then reused by phase B)
  // phase A
  float* Af32 = (float*)(AR + 0);
  u16* Ahi    = (u16*)(AR + 16 * MBy);
  u16* Alo    = (u16*)(AR + 24 * MBy);
  float* Xf32 = (float*)(AR + 32 * MBy);
  u16* Xhi    = (u16*)(AR + 48 * MBy);
  u16* Xlo    = (u16*)(AR + 56 * MBy);
  u16* XThi   = (u16*)(AR + 64 * MBy);
  u16* XTlo   = (u16*)(AR + 72 * MBy);
  u16* WThi   = (u16*)(AR + 80 * MBy);
  u16* WTlo   = (u16*)(AR + 88 * MBy);
  float* T    = (float*)(AR + 96 * MBy);   // 8 planes f32
  u16* VsHi   = (u16*)(AR + 144 * MBy);
  u16* VsLo   = (u16*)(AR + 148 * MBy);
  u16* UHi    = (u16*)(AR + 152 * MBy);
  u16* ULo    = (u16*)(AR + 156 * MBy);
  u16* UsHi   = (u16*)(AR + 160 * MBy);
  u16* VHi    = (u16*)(AR + 164 * MBy);
  u16* MiT    = (u16*)(AR + 168 * MBy);    // ReT_hi, ImT_hi, ReT_lo, ImT_lo
  u16* W_hi   = (u16*)(AR + 176 * MBy);
  u16* W_lo   = (u16*)(AR + 184 * MBy);
  float* G_f  = (float*)(AR + 192 * MBy);
  // phase B (reuses arena)
  u16* Hb     = (u16*)(AR + 0);
  u16* XbHi   = (u16*)(AR + 16 * MBy);
  u16* XbLo   = (u16*)(AR + 32 * MBy);
  u16* HtRe   = (u16*)(AR + 48 * MBy);
  u16* HtIm   = (u16*)(AR + 64 * MBy);
  u16* XtRe   = (u16*)(AR + 80 * MBy);
  u16* XtIm   = (u16*)(AR + 96 * MBy);
  float* delta= (float*)(AR + 112 * MBy);
  u16* HnRe   = (u16*)(AR + 176 * MBy);
  u16* HnIm   = (u16*)(AR + 192 * MBy);

  dim3 b256(256);
  const dim3 gdd(4096, 2);

  // ---- Phase A: Cayley(U), Cayley(V) via Newton ----
  k_buildA<<<gdd, b256, 0, stream>>>(ur, ui, vr, vi, Af32, Ahi, Alo);

  {  // A^2 (Bt = A planes; skew-Hermitian sign handled in k_x0)
    ZP z[8];
    for (int y = 0; y < 2; ++y) {
      const u16* are = Ahi + (size_t)y * 2 * DD; const u16* aim = are + DD;
      float* t = T + (size_t)y * 4 * DD;
      z[y*4+0] = {are, nullptr, are, nullptr, t,          1.f, 0.f};
      z[y*4+1] = {aim, nullptr, aim, nullptr, t + DD,     1.f, 0.f};
      z[y*4+2] = {are, nullptr, aim, nullptr, t + 2*DD,   1.f, 0.f};
      z[y*4+3] = {aim, nullptr, are, nullptr, t + 3*DD,   1.f, 0.f};
    }
    launch_gemm(false, false, 1024, 1024, 1024, 1024, 1024, 1024, 1, 8, z, stream);
  }
  k_x0<<<gdd, b256, 0, stream>>>(Af32, T, Xf32, Xhi, XThi);

  for (int it = 0; it < 3; ++it) {  // bf16 Newton iterations
    {  // Q = A@X
      ZP z[8];
      for (int y = 0; y < 2; ++y) {
        const u16* are = Ahi + (size_t)y*2*DD; const u16* aim = are + DD;
        const u16* xtr = XThi + (size_t)y*2*DD; const u16* xti = xtr + DD;
        float* t = T + (size_t)y*4*DD;
        z[y*4+0] = {are, nullptr, xtr, nullptr, t,        1.f, 0.f};
        z[y*4+1] = {aim, nullptr, xti, nullptr, t + DD,   1.f, 0.f};
        z[y*4+2] = {are, nullptr, xti, nullptr, t + 2*DD, 1.f, 0.f};
        z[y*4+3] = {aim, nullptr, xtr, nullptr, t + 3*DD, 1.f, 0.f};
      }
      launch_gemm(false, false, 1024, 1024, 1024, 1024, 1024, 1024, 1, 8, z, stream);
    }
    k_wt<<<gdd, b256, 0, stream>>>(Xf32, T, WThi, nullptr);
    {  // X' = X@W
      ZP z[8];
      for (int y = 0; y < 2; ++y) {
        const u16* xre = Xhi + (size_t)y*2*DD; const u16* xim = xre + DD;
        const u16* wtr = WThi + (size_t)y*2*DD; const u16* wti = wtr + DD;
        float* t = T + (size_t)y*4*DD;
        z[y*4+0] = {xre, nullptr, wtr, nullptr, t,        1.f, 0.f};
        z[y*4+1] = {xim, nullptr, wti, nullptr, t + DD,   1.f, 0.f};
        z[y*4+2] = {xre, nullptr, wti, nullptr, t + 2*DD, 1.f, 0.f};
        z[y*4+3] = {xim, nullptr, wtr, nullptr, t + 3*DD, 1.f, 0.f};
      }
      launch_gemm(false, false, 1024, 1024, 1024, 1024, 1024, 1024, 1, 8, z, stream);
    }
    const bool last = (it == 2);
    k_xn<<<gdd, b256, 0, stream>>>(T, Xf32, Xhi, XThi,
                                   last ? Xlo : nullptr, last ? XTlo : nullptr);
  }

  {  // refinement: Q = A@X in split precision
    ZP z[8];
    for (int y = 0; y < 2; ++y) {
      const u16* areh = Ahi + (size_t)y*2*DD; const u16* aimh = areh + DD;
      const u16* arel = Alo + (size_t)y*2*DD; const u16* aiml = arel + DD;
      const u16* xtrh = XThi + (size_t)y*2*DD; const u16* xtih = xtrh + DD;
      const u16* xtrl = XTlo + (size_t)y*2*DD; const u16* xtil = xtrl + DD;
      float* t = T + (size_t)y*4*DD;
      z[y*4+0] = {areh, arel, xtrh, xtrl, t,        1.f, 0.f};
      z[y*4+1] = {aimh, aiml, xtih, xtil, t + DD,   1.f, 0.f};
      z[y*4+2] = {areh, arel, xtih, xtil, t + 2*DD, 1.f, 0.f};
      z[y*4+3] = {aimh, aiml, xtrh, xtrl, t + 3*DD, 1.f, 0.f};
    }
    launch_gemm(true, false, 1024, 1024, 1024, 1024, 1024, 1024, 1, 8, z, stream);
  }
  k_wt<<<gdd, b256, 0, stream>>>(Xf32, T, WThi, WTlo);
  {  // Xr = X@W in split precision
    ZP z[8];
    for (int y = 0; y < 2; ++y) {
      const u16* xreh = Xhi + (size_t)y*2*DD; const u16* ximh = xreh + DD;
      const u16* xrel = Xlo + (size_t)y*2*DD; const u16* ximl = xrel + DD;
      const u16* wtrh = WThi + (size_t)y*2*DD; const u16* wtih = wtrh + DD;
      const u16* wtrl = WTlo + (size_t)y*2*DD; const u16* wtil = wtrl + DD;
      float* t = T + (size_t)y*4*DD;
      z[y*4+0] = {xreh, xrel, wtrh, wtrl, t,        1.f, 0.f};
      z[y*4+1] = {ximh, ximl, wtih, wtil, t + DD,   1.f, 0.f};
      z[y*4+2] = {xreh, xrel, wtih, wtil, t + 2*DD, 1.f, 0.f};
      z[y*4+3] = {ximh, ximl, wtrh, wtrl, t + 3*DD, 1.f, 0.f};
    }
    launch_gemm(true, false, 1024, 1024, 1024, 1024, 1024, 1024, 1, 8, z, stream);
  }
  k_finalUV<<<gdd, b256, 0, stream>>>(T, logsig, VsHi, VsLo, UHi, ULo, UsHi, VHi);

  {  // M_inv = (V s_inv) @ U^H (split)
    ZP z[4] = {
      {VsHi,      VsLo,      UHi,      ULo,      T,        1.f, 0.f},
      {VsHi + DD, VsLo + DD, UHi + DD, ULo + DD, T + DD,   1.f, 0.f},
      {VsHi + DD, VsLo + DD, UHi,      ULo,      T + 2*DD, 1.f, 0.f},
      {VsHi,      VsLo,      UHi + DD, ULo + DD, T + 3*DD, 1.f, 0.f}};
    launch_gemm(true, false, 1024, 1024, 1024, 1024, 1024, 1024, 1, 4, z, stream);
  }
  {  // M = (U s) @ V^H (plain)
    ZP z[4] = {
      {UsHi,      nullptr, VHi,      nullptr, T + 4*DD, 1.f, 0.f},
      {UsHi + DD, nullptr, VHi + DD, nullptr, T + 5*DD, 1.f, 0.f},
      {UsHi + DD, nullptr, VHi,      nullptr, T + 6*DD, 1.f, 0.f},
      {UsHi,      nullptr, VHi + DD, nullptr, T + 7*DD, 1.f, 0.f}};
    launch_gemm(false, false, 1024, 1024, 1024, 1024, 1024, 1024, 1, 4, z, stream);
  }
  k_cmb_M<<<dim3(4096), b256, 0, stream>>>(T, MiRe_b, MiIm_b, MiT, MRe_b, MIm_b);

  // G = W1 @ Re(Mi)^T + W2 @ Im(Mi)^T  (split precision)
  k_split<<<dim3(16384), b256, 0, stream>>>(sel_w, W_hi, W_lo, (size_t)2048 * 2048);
  {
    ZP z1[1] = {{W_hi, W_lo, MiT, MiT + 2*DD, G_f, 1.f, 0.f}};
    launch_gemm(true, false, 2048, 1024, 1024, 2048, 1024, 1024, 1, 1, z1, stream);
  }
  {
    ZP z1[1] = {{W_hi + 1024, W_lo + 1024, MiT + DD, MiT + 3*DD, G_f, 1.f, 1.f}};
    launch_gemm(true, false, 2048, 1024, 1024, 2048, 1024, 1024, 1, 1, z1, stream);
  }
  k_split<<<dim3(8192), b256, 0, stream>>>(G_f, G_hi, G_lo, (size_t)2048 * 1024);

  // ---- Phase B ----
  k_split<<<dim3(32768), b256, 0, stream>>>(x_input, XbHi, XbLo, BD);
  k_split<<<dim3(32768), b256, 0, stream>>>(h_prev, Hb, nullptr, BD);
  {  // encode: h_tilde / x_tilde (bf16 out)
    ZP z[4] = {
      {Hb,   nullptr, MiRe_b, nullptr, HtRe, 1.f, 0.f},
      {Hb,   nullptr, MiIm_b, nullptr, HtIm, 1.f, 0.f},
      {XbHi, nullptr, MiRe_b, nullptr, XtRe, 1.f, 0.f},
      {XbHi, nullptr, MiIm_b, nullptr, XtIm, 1.f, 0.f}};
    launch_gemm(false, true, 8192, 1024, 1024, 1024, 1024, 1024, 1, 4, z, stream);
  }
  {  // delta = x_input @ G^T (split precision)
    ZP z1[1] = {{XbHi, XbLo, G_hi, G_lo, delta, 1.f, 0.f}};
    launch_gemm(true, false, 8192, 2048, 1024, 1024, 1024, 2048, 1, 1, z1, stream);
  }
  k_pointwise<<<dim3(32768), b256, 0, stream>>>(HtRe, HtIm, XtRe, XtIm, delta, dt, ld, lf, dts,
                                                sre, sim, lwre, lwim, sel_b, HnRe, HnIm);

  if (realOnly) {
    // out = Re(h_next @ M^T) = HnRe@MRe^T - HnIm@MIm^T  (f32, ldc=1024)
    ZP z1[1] = {{HnRe, nullptr, MRe_b, nullptr, out, 1.f, 0.f}};
    launch_gemm(false, false, 8192, 1024, 1024, 1024, 1024, 1024, 1, 1, z1, stream);
    ZP z2[1] = {{HnIm, nullptr, MIm_b, nullptr, out, -1.f, 1.f}};
    launch_gemm(false, false, 8192, 1024, 1024, 1024, 1024, 1024, 1, 1, z2, stream);
  } else {
    {  // interleaved complex out, pass 1
      ZP z[2] = {
        {HnRe, nullptr, MRe_b, nullptr, out,     1.f, 0.f},
        {HnRe, nullptr, MIm_b, nullptr, out + 1, 1.f, 0.f}};
      launch_gemm(false, false, 8192, 1024, 1024, 1024, 1024, 2048, 2, 2, z, stream);
    }
    {  // pass 2 (accumulate)
      ZP z[2] = {
        {HnIm, nullptr, MIm_b, nullptr, out,     -1.f, 1.f},
        {HnIm, nullptr, MRe_b, nullptr, out + 1,  1.f, 1.f}};
      launch_gemm(false, false, 8192, 1024, 1024, 1024, 1024, 2048, 2, 2, z, stream);
    }
  }
}

// Round 3
// 1228.849 us; speedup vs baseline: 1.0166x; 1.0166x over previous
//
#include <hip/hip_runtime.h>
#include <hip/hip_bf16.h>

#define Dd 1024
#define Bb 8192

typedef unsigned short u16;
typedef __attribute__((ext_vector_type(8))) short short8;
typedef __attribute__((ext_vector_type(4))) float f32x4;

static constexpr size_t DD  = (size_t)Dd * Dd;   // 1M
static constexpr size_t BD  = (size_t)Bb * Dd;   // 8M
static constexpr size_t MBy = 1ull << 20;

__device__ __forceinline__ float bf2f(u16 v) {
  union { unsigned u; float f; } c; c.u = ((unsigned)v) << 16; return c.f;
}
__device__ __forceinline__ u16 f2bf(float f) {
  union { float f; unsigned u; } c; c.f = f;
  return (u16)((c.u + 0x7fffu + ((c.u >> 16) & 1u)) >> 16);
}

// ---------------- NT GEMM: C[m][n] = alpha * sum_k A[m][k]*Bt[n][k] (+beta*C) ----------
// A: M x K row-major bf16 ; Bt: N x K row-major bf16 ; C: f32 or bf16
// MODE 0: 1 MFMA (Ah*Bh)          — plain
// MODE 1: 3 MFMA (AhBh+AlBh+AhBl) — split-precision product
// MODE 2: 2 MFMA (AhBh+AlBl)      — pair accumulate (two independent products)
struct ZP { const u16* Ah; const u16* Al; const u16* Bh; const u16* Bl; void* C; float alpha; float beta; };
struct GArgs { ZP z[8]; int K, lda, ldb; long ldc; int cstride; };

template<int MODE, bool OBF>
__global__ __launch_bounds__(256) void gemm_nt(GArgs a) {
  constexpr bool X2 = (MODE != 0);
  __shared__ __align__(16) u16 smem[X2 ? 32768 : 16384];
  u16* As = smem;
  u16* Bs = smem + 8192;
  const ZP p = a.z[blockIdx.z];
  const int tid  = threadIdx.x;
  const int lane = tid & 63, wv = tid >> 6;

  // XCD-chunked swizzle (bijective when nwg%8==0): blocks sharing an A-row-panel
  // stay on one XCD's L2 -> A fetched once instead of x8.  [T1, m157/m204]
  int bx = blockIdx.x, by = blockIdx.y;
  {
    const int gx = gridDim.x;
    const int nwg = gx * gridDim.y;
    if ((nwg & 7) == 0 && nwg >= 16) {
      const int flat = by * gx + bx;
      const int ch = nwg >> 3;
      const int nf = (flat & 7) * ch + (flat >> 3);
      bx = nf % gx; by = nf / gx;
    }
  }

  const long brow = (long)by * 128, bcol = (long)bx * 128;
  const int wm = (wv & 1) * 64, wn = (wv >> 1) * 64;
  const int srow = wv * 8 + (lane >> 3);
  const int scol = (lane & 7) * 8;
  f32x4 acc[4][4];
#pragma unroll
  for (int i = 0; i < 4; ++i)
#pragma unroll
    for (int j = 0; j < 4; ++j) { f32x4 zv = {0.f, 0.f, 0.f, 0.f}; acc[i][j] = zv; }

  for (int kt = 0; kt < a.K; kt += 64) {
    __syncthreads();
#pragma unroll
    for (int i = 0; i < 4; ++i) {
      const int rr = i * 32 + srow;
      const int lb = (i * 32 + wv * 8) * 64;
      const u16* ga = p.Ah + (brow + rr) * (long)a.lda + kt + scol;
      const u16* gb = p.Bh + (bcol + rr) * (long)a.ldb + kt + scol;
      __builtin_amdgcn_global_load_lds((const __attribute__((address_space(1))) void*)ga,
                                       (__attribute__((address_space(3))) void*)(As + lb), 16, 0, 0);
      __builtin_amdgcn_global_load_lds((const __attribute__((address_space(1))) void*)gb,
                                       (__attribute__((address_space(3))) void*)(Bs + lb), 16, 0, 0);
      if constexpr (X2) {
        const u16* ga2 = p.Al + (brow + rr) * (long)a.lda + kt + scol;
        const u16* gb2 = p.Bl + (bcol + rr) * (long)a.ldb + kt + scol;
        __builtin_amdgcn_global_load_lds((const __attribute__((address_space(1))) void*)ga2,
                                         (__attribute__((address_space(3))) void*)(smem + 16384 + lb), 16, 0, 0);
        __builtin_amdgcn_global_load_lds((const __attribute__((address_space(1))) void*)gb2,
                                         (__attribute__((address_space(3))) void*)(smem + 24576 + lb), 16, 0, 0);
      }
    }
    __syncthreads();
#pragma unroll
    for (int kk = 0; kk < 64; kk += 32) {
      const int ko = kk + ((lane >> 4) * 8);
      short8 af[4], bfv[4], al[4], bl[4];
#pragma unroll
      for (int i = 0; i < 4; ++i) {
        af[i]  = *(const short8*)(As + (wm + i * 16 + (lane & 15)) * 64 + ko);
        bfv[i] = *(const short8*)(Bs + (wn + i * 16 + (lane & 15)) * 64 + ko);
        if constexpr (X2) {
          al[i] = *(const short8*)(smem + 16384 + (wm + i * 16 + (lane & 15)) * 64 + ko);
          bl[i] = *(const short8*)(smem + 24576 + (wn + i * 16 + (lane & 15)) * 64 + ko);
        }
      }
#pragma unroll
      for (int i = 0; i < 4; ++i)
#pragma unroll
        for (int j = 0; j < 4; ++j) {
          acc[i][j] = __builtin_amdgcn_mfma_f32_16x16x32_bf16(af[i], bfv[j], acc[i][j], 0, 0, 0);
          if constexpr (MODE == 1) {
            acc[i][j] = __builtin_amdgcn_mfma_f32_16x16x32_bf16(al[i], bfv[j], acc[i][j], 0, 0, 0);
            acc[i][j] = __builtin_amdgcn_mfma_f32_16x16x32_bf16(af[i], bl[j], acc[i][j], 0, 0, 0);
          } else if constexpr (MODE == 2) {
            acc[i][j] = __builtin_amdgcn_mfma_f32_16x16x32_bf16(al[i], bl[j], acc[i][j], 0, 0, 0);
          }
        }
    }
  }
  const long crow = brow + wm + ((lane >> 4) * 4);
  const long ccol = bcol + wn + (lane & 15);
#pragma unroll
  for (int i = 0; i < 4; ++i)
#pragma unroll
    for (int j = 0; j < 4; ++j)
#pragma unroll
      for (int r = 0; r < 4; ++r) {
        const long cidx = (crow + i * 16 + r) * a.ldc + (ccol + j * 16) * (long)a.cstride;
        float v = acc[i][j][r] * p.alpha;
        if constexpr (OBF) {
          ((u16*)p.C)[cidx] = f2bf(v);
        } else {
          float* C = (float*)p.C;
          if (p.beta != 0.0f) v += p.beta * C[cidx];
          C[cidx] = v;
        }
      }
}

// ---------------- elementwise kernels ----------------
// planes layout for complex d x d sets: [y*2*DD + 0] = re, [y*2*DD + DD] = im, y in {0(u),1(v)}

__global__ void k_buildA(const float* ur, const float* ui, const float* vr, const float* vi,
                         float* Af32, u16* Ahi, u16* Alo) {
  const int y = blockIdx.y;
  const size_t idx = (size_t)blockIdx.x * 256 + threadIdx.x;
  const size_t r = idx >> 10, c = idx & 1023;
  const float* re = y ? vr : ur; const float* im = y ? vi : ui;
  float are = 0.5f * (re[idx] - re[c * Dd + r]);
  float aim = 0.5f * (im[idx] + im[c * Dd + r]);
  size_t pr = (size_t)y * 2 * DD + idx, pi = pr + DD;
  Af32[pr] = are; Af32[pi] = aim;
  u16 h = f2bf(are); Ahi[pr] = h; Alo[pr] = f2bf(are - bf2f(h));
  h = f2bf(aim); Ahi[pi] = h; Alo[pi] = f2bf(aim - bf2f(h));
}

// X0 = I + A + A^2 ;  A^2: re = -T0-T1, im = T2-T3 (skew-Hermitian Bt trick)
__global__ void k_x0(const float* Af32, const float* T, float* Xf32, u16* Xhi, u16* XThi) {
  const int y = blockIdx.y;
  const size_t idx = (size_t)blockIdx.x * 256 + threadIdx.x;
  const size_t r = idx >> 10, c = idx & 1023;
  const size_t t0 = (size_t)y * 4 * DD + idx;
  float a2re = -T[t0] - T[t0 + DD];
  float a2im =  T[t0 + 2 * DD] - T[t0 + 3 * DD];
  size_t pr = (size_t)y * 2 * DD + idx, pi = pr + DD;
  float xre = Af32[pr] + a2re + (r == c ? 1.0f : 0.0f);
  float xim = Af32[pi] + a2im;
  Xf32[pr] = xre; Xf32[pi] = xim;
  Xhi[pr] = f2bf(xre); Xhi[pi] = f2bf(xim);
  size_t tr = c * Dd + r;
  size_t qr = (size_t)y * 2 * DD + tr;
  XThi[qr] = f2bf(xre); XThi[qr + DD] = f2bf(xim);
}

// Wt[n][k] = (2I - X + Q)[k][n] ; Q: re = T0-T1, im = T2+T3
__global__ void k_wt(const float* Xf32, const float* T, u16* WThi, u16* WTlo) {
  const int y = blockIdx.y;
  const size_t idx = (size_t)blockIdx.x * 256 + threadIdx.x;  // write index: n*Dd + k
  const size_t n = idx >> 10, k = idx & 1023;
  const size_t ridx = k * Dd + n;
  const size_t t0 = (size_t)y * 4 * DD;
  float qre = T[t0 + ridx] - T[t0 + DD + ridx];
  float qim = T[t0 + 2 * DD + ridx] + T[t0 + 3 * DD + ridx];
  size_t pr = (size_t)y * 2 * DD, pi = pr + DD;
  float wre = (n == k ? 2.0f : 0.0f) - Xf32[pr + ridx] + qre;
  float wim = -Xf32[pi + ridx] + qim;
  u16 h = f2bf(wre); WThi[pr + idx] = h;
  if (WTlo) WTlo[pr + idx] = f2bf(wre - bf2f(h));
  h = f2bf(wim); WThi[pi + idx] = h;
  if (WTlo) WTlo[pi + idx] = f2bf(wim - bf2f(h));
}

// X' = X@W : re = T0-T1, im = T2+T3 ; optionally emit hi/lo splits (pre-refinement)
__global__ void k_xn(const float* T, float* Xf32, u16* Xhi, u16* XThi, u16* Xlo, u16* XTlo) {
  const int y = blockIdx.y;
  const size_t idx = (size_t)blockIdx.x * 256 + threadIdx.x;
  const size_t r = idx >> 10, c = idx & 1023;
  const size_t t0 = (size_t)y * 4 * DD + idx;
  float xre = T[t0] - T[t0 + DD];
  float xim = T[t0 + 2 * DD] + T[t0 + 3 * DD];
  size_t pr = (size_t)y * 2 * DD + idx, pi = pr + DD;
  Xf32[pr] = xre; Xf32[pi] = xim;
  u16 hr = f2bf(xre), hi_ = f2bf(xim);
  Xhi[pr] = hr; Xhi[pi] = hi_;
  size_t tr = (size_t)y * 2 * DD + c * Dd + r;
  XThi[tr] = hr; XThi[tr + DD] = hi_;
  if (Xlo) {
    u16 lr = f2bf(xre - bf2f(hr)), li = f2bf(xim - bf2f(hi_));
    Xlo[pr] = lr; Xlo[pi] = li;
    XTlo[tr] = lr; XTlo[tr + DD] = li;
  }
}

// From refined T (X@W): Cay = 2X-I ; emit GEMM operands for M / M_inv
__global__ void k_finalUV(const float* T, const float* logsig,
                          u16* VsHi, u16* VsLo, u16* UHi, u16* ULo, u16* UsHi, u16* VHi) {
  const int y = blockIdx.y;
  const size_t idx = (size_t)blockIdx.x * 256 + threadIdx.x;
  const size_t r = idx >> 10, c = idx & 1023;
  const size_t t0 = (size_t)y * 4 * DD + idx;
  float xre = 2.0f * (T[t0] - T[t0 + DD]) - (r == c ? 1.0f : 0.0f);
  float xim = 2.0f * (T[t0 + 2 * DD] + T[t0 + 3 * DD]);
  if (y == 0) {  // U:  hi/lo (Bt of M_inv) ; U*s hi (A of M)
    float s = expf(logsig[c]);
    u16 h = f2bf(xre); UHi[idx] = h; ULo[idx] = f2bf(xre - bf2f(h));
    h = f2bf(xim); UHi[DD + idx] = h; ULo[DD + idx] = f2bf(xim - bf2f(h));
    UsHi[idx] = f2bf(xre * s); UsHi[DD + idx] = f2bf(xim * s);
  } else {       // V:  hi (Bt of M) ; V*s_inv hi/lo (A of M_inv)
    float si = expf(-logsig[c]);
    VHi[idx] = f2bf(xre); VHi[DD + idx] = f2bf(xim);
    float a = xre * si, b = xim * si;
    u16 h = f2bf(a); VsHi[idx] = h; VsLo[idx] = f2bf(a - bf2f(h));
    h = f2bf(b); VsHi[DD + idx] = h; VsLo[DD + idx] = f2bf(b - bf2f(h));
  }
}

// M_inv = T0+T1, T2-T3 ; M = T4+T5, T6-T7 ; also transposed hi/lo of M_inv for G
__global__ void k_cmb_M(const float* T, u16* MiRe, u16* MiIm, u16* MiT, u16* MRe, u16* MIm) {
  const size_t idx = (size_t)blockIdx.x * 256 + threadIdx.x;
  const size_t r = idx >> 10, c = idx & 1023;
  float mire = T[idx] + T[DD + idx];
  float miim = T[2 * DD + idx] - T[3 * DD + idx];
  float mre  = T[4 * DD + idx] + T[5 * DD + idx];
  float mim  = T[6 * DD + idx] - T[7 * DD + idx];
  MiRe[idx] = f2bf(mire); MiIm[idx] = f2bf(miim);
  MRe[idx]  = f2bf(mre);  MIm[idx]  = f2bf(mim);
  size_t tr = c * Dd + r;
  u16 h = f2bf(mire); MiT[tr] = h;          MiT[2 * DD + tr] = f2bf(mire - bf2f(h));
  h = f2bf(miim);     MiT[DD + tr] = h;     MiT[3 * DD + tr] = f2bf(miim - bf2f(h));
}

__global__ void k_split(const float* src, u16* hi, u16* lo, size_t n) {
  const size_t idx = (size_t)blockIdx.x * 256 + threadIdx.x;
  if (idx >= n) return;
  float v = src[idx]; u16 h = f2bf(v); hi[idx] = h;
  if (lo) lo[idx] = f2bf(v - bf2f(h));
}

__global__ void k_pointwise(const u16* HtRe, const u16* HtIm, const u16* XtRe, const u16* XtIm,
                            const float* delta, const float* dt, const float* ld, const float* lf,
                            const float* dts, const float* sre, const float* sim,
                            const float* lwre, const float* lwim, const float* selb,
                            u16* HnRe, u16* HnIm, float imSign) {
  const size_t idx = (size_t)blockIdx.x * 256 + threadIdx.x;  // < BD
  const int b = (int)(idx >> 10); const int c = (int)(idx & 1023);
  float dre = delta[(size_t)b * 2048 + c] + selb[c];
  float dim = delta[(size_t)b * 2048 + 1024 + c] + selb[1024 + c];
  float lamre = -expf(ld[c]) + lwre[c] + dre;
  float lamim = lf[c] + lwim[c] + dim;
  float dtv = dt[b];
  float dtn = dtv / dts[c];
  float zre = lamre * dtn, zim = lamim * dtn;
  float r2 = zre * zre + zim * zim;
  float er = expf(zre); float sn, cs; __sincosf(zim, &sn, &cs);
  float dcre = er * cs, dcim = er * sn;
  float p1re, p1im;
  if (r2 < 1e-8f) {
    p1re = 1.0f + 0.5f * zre + (zre * zre - zim * zim) * (1.0f / 6.0f);
    p1im = 0.5f * zim + (zre * zim) * (1.0f / 3.0f);
  } else {
    float inv = 1.0f / r2;
    float nre = dcre - 1.0f, nim = dcim;
    p1re = (nre * zre + nim * zim) * inv;
    p1im = (nim * zre - nre * zim) * inv;
  }
  float fre = p1re * dtv, fim = p1im * dtv;  // phi1 * dt
  float hre = bf2f(HtRe[idx]), him = bf2f(HtIm[idx]);
  float xre = bf2f(XtRe[idx]) + sre[c], xim = bf2f(XtIm[idx]) + sim[c];
  float ore = hre * dcre - him * dcim + xre * fre - xim * fim;
  float oim = hre * dcim + him * dcre + xre * fim + xim * fre;
  HnRe[idx] = f2bf(ore); HnIm[idx] = f2bf(imSign * oim);
}

__global__ void k_fill(float* p, size_t n, float v) {
  const size_t idx = (size_t)blockIdx.x * 256 + threadIdx.x;
  if (idx < n) p[idx] = v;
}

// ---------------- host ----------------
static void launch_gemm(int mode, bool obf, int M, int N, int K, int lda, int ldb,
                        long ldc, int cstride, int nz, const ZP* z, hipStream_t s) {
  GArgs a; a.K = K; a.lda = lda; a.ldb = ldb; a.ldc = ldc; a.cstride = cstride;
  for (int i = 0; i < 8; ++i) a.z[i] = z[i < nz ? i : 0];
  dim3 g(N / 128, M / 128, nz), blk(256);
  if (mode == 1)      gemm_nt<1, false><<<g, blk, 0, s>>>(a);
  else if (mode == 2) gemm_nt<2, false><<<g, blk, 0, s>>>(a);
  else if (obf)       gemm_nt<0, true ><<<g, blk, 0, s>>>(a);
  else                gemm_nt<0, false><<<g, blk, 0, s>>>(a);
}

extern "C" void kernel_launch(void* const* d_in, const int* in_sizes, int n_in,
                              void* d_out, int out_size, void* d_ws, size_t ws_size,
                              hipStream_t stream) {
  const float* h_prev  = (const float*)d_in[0];
  const float* x_input = (const float*)d_in[1];
  const float* dt      = (const float*)d_in[2];
  const float* ur      = (const float*)d_in[3];
  const float* ui      = (const float*)d_in[4];
  const float* vr      = (const float*)d_in[5];
  const float* vi      = (const float*)d_in[6];
  const float* logsig  = (const float*)d_in[7];
  const float* ld      = (const float*)d_in[8];
  const float* lf      = (const float*)d_in[9];
  const float* dts     = (const float*)d_in[10];
  const float* sre     = (const float*)d_in[11];
  const float* sim     = (const float*)d_in[12];
  const float* lwre    = (const float*)d_in[13];
  const float* lwim    = (const float*)d_in[14];
  const float* sel_w   = (const float*)d_in[15];
  const float* sel_b   = (const float*)d_in[16];
  float* out = (float*)d_out;
  char* ws = (char*)d_ws;

  const bool realOnly = ((size_t)out_size == BD);
  const bool interleaved = ((size_t)out_size == 2 * BD);
  if ((!realOnly && !interleaved) || ws_size < 224 * MBy) {
    k_fill<<<dim3(((size_t)out_size + 255) / 256), dim3(256), 0, stream>>>(out, (size_t)out_size, 1e9f);
    return;
  }

  // persistent region [0,16MB)
  u16* MiRe_b = (u16*)(ws + 0 * MBy);
  u16* MiIm_b = (u16*)(ws + 2 * MBy);
  u16* MRe_b  = (u16*)(ws + 4 * MBy);
  u16* MIm_b  = (u16*)(ws + 6 * MBy);
  u16* G_hi   = (u16*)(ws + 8 * MBy);
  u16* G_lo   = (u16*)(ws + 12 * MBy);
  char* AR = ws + 16 * MBy;  // arena (phase A then reused by phase B)
  // phase A
  float* Af32 = (float*)(AR + 0);
  u16* Ahi    = (u16*)(AR + 16 * MBy);
  u16* Alo    = (u16*)(AR + 24 * MBy);
  float* Xf32 = (float*)(AR + 32 * MBy);
  u16* Xhi    = (u16*)(AR + 48 * MBy);
  u16* Xlo    = (u16*)(AR + 56 * MBy);
  u16* XThi   = (u16*)(AR + 64 * MBy);
  u16* XTlo   = (u16*)(AR + 72 * MBy);
  u16* WThi   = (u16*)(AR + 80 * MBy);
  u16* WTlo   = (u16*)(AR + 88 * MBy);
  float* T    = (float*)(AR + 96 * MBy);   // 8 planes f32
  u16* VsHi   = (u16*)(AR + 144 * MBy);
  u16* VsLo   = (u16*)(AR + 148 * MBy);
  u16* UHi    = (u16*)(AR + 152 * MBy);
  u16* ULo    = (u16*)(AR + 156 * MBy);
  u16* UsHi   = (u16*)(AR + 160 * MBy);
  u16* VHi    = (u16*)(AR + 164 * MBy);
  u16* MiT    = (u16*)(AR + 168 * MBy);    // ReT_hi, ImT_hi, ReT_lo, ImT_lo
  u16* W_hi   = (u16*)(AR + 176 * MBy);
  u16* W_lo   = (u16*)(AR + 184 * MBy);
  float* G_f  = (float*)(AR + 192 * MBy);
  // phase B (reuses arena)
  u16* Hb     = (u16*)(AR + 0);
  u16* XbHi   = (u16*)(AR + 16 * MBy);
  u16* XbLo   = (u16*)(AR + 32 * MBy);
  u16* HtRe   = (u16*)(AR + 48 * MBy);
  u16* HtIm   = (u16*)(AR + 64 * MBy);
  u16* XtRe   = (u16*)(AR + 80 * MBy);
  u16* XtIm   = (u16*)(AR + 96 * MBy);
  float* delta= (float*)(AR + 112 * MBy);
  u16* HnRe   = (u16*)(AR + 176 * MBy);
  u16* HnIm   = (u16*)(AR + 192 * MBy);

  dim3 b256(256);
  const dim3 gdd(4096, 2);

  // ---- Phase A: Cayley(U), Cayley(V) via Newton ----
  k_buildA<<<gdd, b256, 0, stream>>>(ur, ui, vr, vi, Af32, Ahi, Alo);

  {  // A^2 (Bt = A planes; skew-Hermitian sign handled in k_x0)
    ZP z[8];
    for (int y = 0; y < 2; ++y) {
      const u16* are = Ahi + (size_t)y * 2 * DD; const u16* aim = are + DD;
      float* t = T + (size_t)y * 4 * DD;
      z[y*4+0] = {are, nullptr, are, nullptr, t,          1.f, 0.f};
      z[y*4+1] = {aim, nullptr, aim, nullptr, t + DD,     1.f, 0.f};
      z[y*4+2] = {are, nullptr, aim, nullptr, t + 2*DD,   1.f, 0.f};
      z[y*4+3] = {aim, nullptr, are, nullptr, t + 3*DD,   1.f, 0.f};
    }
    launch_gemm(0, false, 1024, 1024, 1024, 1024, 1024, 1024, 1, 8, z, stream);
  }
  k_x0<<<gdd, b256, 0, stream>>>(Af32, T, Xf32, Xhi, XThi);

  for (int it = 0; it < 3; ++it) {  // bf16 Newton iterations
    {  // Q = A@X
      ZP z[8];
      for (int y = 0; y < 2; ++y) {
        const u16* are = Ahi + (size_t)y*2*DD; const u16* aim = are + DD;
        const u16* xtr = XThi + (size_t)y*2*DD; const u16* xti = xtr + DD;
        float* t = T + (size_t)y*4*DD;
        z[y*4+0] = {are, nullptr, xtr, nullptr, t,        1.f, 0.f};
        z[y*4+1] = {aim, nullptr, xti, nullptr, t + DD,   1.f, 0.f};
        z[y*4+2] = {are, nullptr, xti, nullptr, t + 2*DD, 1.f, 0.f};
        z[y*4+3] = {aim, nullptr, xtr, nullptr, t + 3*DD, 1.f, 0.f};
      }
      launch_gemm(0, false, 1024, 1024, 1024, 1024, 1024, 1024, 1, 8, z, stream);
    }
    k_wt<<<gdd, b256, 0, stream>>>(Xf32, T, WThi, nullptr);
    {  // X' = X@W
      ZP z[8];
      for (int y = 0; y < 2; ++y) {
        const u16* xre = Xhi + (size_t)y*2*DD; const u16* xim = xre + DD;
        const u16* wtr = WThi + (size_t)y*2*DD; const u16* wti = wtr + DD;
        float* t = T + (size_t)y*4*DD;
        z[y*4+0] = {xre, nullptr, wtr, nullptr, t,        1.f, 0.f};
        z[y*4+1] = {xim, nullptr, wti, nullptr, t + DD,   1.f, 0.f};
        z[y*4+2] = {xre, nullptr, wti, nullptr, t + 2*DD, 1.f, 0.f};
        z[y*4+3] = {xim, nullptr, wtr, nullptr, t + 3*DD, 1.f, 0.f};
      }
      launch_gemm(0, false, 1024, 1024, 1024, 1024, 1024, 1024, 1, 8, z, stream);
    }
    const bool last = (it == 2);
    k_xn<<<gdd, b256, 0, stream>>>(T, Xf32, Xhi, XThi,
                                   last ? Xlo : nullptr, last ? XTlo : nullptr);
  }

  {  // refinement: Q = A@X in split precision
    ZP z[8];
    for (int y = 0; y < 2; ++y) {
      const u16* areh = Ahi + (size_t)y*2*DD; const u16* aimh = areh + DD;
      const u16* arel = Alo + (size_t)y*2*DD; const u16* aiml = arel + DD;
      const u16* xtrh = XThi + (size_t)y*2*DD; const u16* xtih = xtrh + DD;
      const u16* xtrl = XTlo + (size_t)y*2*DD; const u16* xtil = xtrl + DD;
      float* t = T + (size_t)y*4*DD;
      z[y*4+0] = {areh, arel, xtrh, xtrl, t,        1.f, 0.f};
      z[y*4+1] = {aimh, aiml, xtih, xtil, t + DD,   1.f, 0.f};
      z[y*4+2] = {areh, arel, xtih, xtil, t + 2*DD, 1.f, 0.f};
      z[y*4+3] = {aimh, aiml, xtrh, xtrl, t + 3*DD, 1.f, 0.f};
    }
    launch_gemm(1, false, 1024, 1024, 1024, 1024, 1024, 1024, 1, 8, z, stream);
  }
  k_wt<<<gdd, b256, 0, stream>>>(Xf32, T, WThi, WTlo);
  {  // Xr = X@W in split precision
    ZP z[8];
    for (int y = 0; y < 2; ++y) {
      const u16* xreh = Xhi + (size_t)y*2*DD; const u16* ximh = xreh + DD;
      const u16* xrel = Xlo + (size_t)y*2*DD; const u16* ximl = xrel + DD;
      const u16* wtrh = WThi + (size_t)y*2*DD; const u16* wtih = wtrh + DD;
      const u16* wtrl = WTlo + (size_t)y*2*DD; const u16* wtil = wtrl + DD;
      float* t = T + (size_t)y*4*DD;
      z[y*4+0] = {xreh, xrel, wtrh, wtrl, t,        1.f, 0.f};
      z[y*4+1] = {ximh, ximl, wtih, wtil, t + DD,   1.f, 0.f};
      z[y*4+2] = {xreh, xrel, wtih, wtil, t + 2*DD, 1.f, 0.f};
      z[y*4+3] = {ximh, ximl, wtrh, wtrl, t + 3*DD, 1.f, 0.f};
    }
    launch_gemm(1, false, 1024, 1024, 1024, 1024, 1024, 1024, 1, 8, z, stream);
  }
  k_finalUV<<<gdd, b256, 0, stream>>>(T, logsig, VsHi, VsLo, UHi, ULo, UsHi, VHi);

  {  // M_inv = (V s_inv) @ U^H (split)
    ZP z[4] = {
      {VsHi,      VsLo,      UHi,      ULo,      T,        1.f, 0.f},
      {VsHi + DD, VsLo + DD, UHi + DD, ULo + DD, T + DD,   1.f, 0.f},
      {VsHi + DD, VsLo + DD, UHi,      ULo,      T + 2*DD, 1.f, 0.f},
      {VsHi,      VsLo,      UHi + DD, ULo + DD, T + 3*DD, 1.f, 0.f}};
    launch_gemm(1, false, 1024, 1024, 1024, 1024, 1024, 1024, 1, 4, z, stream);
  }
  {  // M = (U s) @ V^H (plain)
    ZP z[4] = {
      {UsHi,      nullptr, VHi,      nullptr, T + 4*DD, 1.f, 0.f},
      {UsHi + DD, nullptr, VHi + DD, nullptr, T + 5*DD, 1.f, 0.f},
      {UsHi + DD, nullptr, VHi,      nullptr, T + 6*DD, 1.f, 0.f},
      {UsHi,      nullptr, VHi + DD, nullptr, T + 7*DD, 1.f, 0.f}};
    launch_gemm(0, false, 1024, 1024, 1024, 1024, 1024, 1024, 1, 4, z, stream);
  }
  k_cmb_M<<<dim3(4096), b256, 0, stream>>>(T, MiRe_b, MiIm_b, MiT, MRe_b, MIm_b);

  // G = W1 @ Re(Mi)^T + W2 @ Im(Mi)^T  (split precision)
  k_split<<<dim3(16384), b256, 0, stream>>>(sel_w, W_hi, W_lo, (size_t)2048 * 2048);
  {
    ZP z1[1] = {{W_hi, W_lo, MiT, MiT + 2*DD, G_f, 1.f, 0.f}};
    launch_gemm(1, false, 2048, 1024, 1024, 2048, 1024, 1024, 1, 1, z1, stream);
  }
  {
    ZP z1[1] = {{W_hi + 1024, W_lo + 1024, MiT + DD, MiT + 3*DD, G_f, 1.f, 1.f}};
    launch_gemm(1, false, 2048, 1024, 1024, 2048, 1024, 1024, 1, 1, z1, stream);
  }
  k_split<<<dim3(8192), b256, 0, stream>>>(G_f, G_hi, G_lo, (size_t)2048 * 1024);

  // ---- Phase B ----
  k_split<<<dim3(32768), b256, 0, stream>>>(x_input, XbHi, XbLo, BD);
  k_split<<<dim3(32768), b256, 0, stream>>>(h_prev, Hb, nullptr, BD);
  {  // encode: h_tilde / x_tilde (bf16 out)
    ZP z[4] = {
      {Hb,   nullptr, MiRe_b, nullptr, HtRe, 1.f, 0.f},
      {Hb,   nullptr, MiIm_b, nullptr, HtIm, 1.f, 0.f},
      {XbHi, nullptr, MiRe_b, nullptr, XtRe, 1.f, 0.f},
      {XbHi, nullptr, MiIm_b, nullptr, XtIm, 1.f, 0.f}};
    launch_gemm(0, true, 8192, 1024, 1024, 1024, 1024, 1024, 1, 4, z, stream);
  }
  {  // delta = x_input @ G^T (split precision)
    ZP z1[1] = {{XbHi, XbLo, G_hi, G_lo, delta, 1.f, 0.f}};
    launch_gemm(1, false, 8192, 2048, 1024, 1024, 1024, 2048, 1, 1, z1, stream);
  }

  if (realOnly) {
    // fold minus into HnIm (imSign=-1); then out = HnRe@MRe^T + (-HnIm)@MIm^T in ONE dispatch
    k_pointwise<<<dim3(32768), b256, 0, stream>>>(HtRe, HtIm, XtRe, XtIm, delta, dt, ld, lf, dts,
                                                  sre, sim, lwre, lwim, sel_b, HnRe, HnIm, -1.0f);
    ZP z1[1] = {{HnRe, HnIm, MRe_b, MIm_b, out, 1.f, 0.f}};
    launch_gemm(2, false, 8192, 1024, 1024, 1024, 1024, 1024, 1, 1, z1, stream);
  } else {
    k_pointwise<<<dim3(32768), b256, 0, stream>>>(HtRe, HtIm, XtRe, XtIm, delta, dt, ld, lf, dts,
                                                  sre, sim, lwre, lwim, sel_b, HnRe, HnIm, 1.0f);
    {  // interleaved complex out, pass 1
      ZP z[2] = {
        {HnRe, nullptr, MRe_b, nullptr, out,     1.f, 0.f},
        {HnRe, nullptr, MIm_b, nullptr, out + 1, 1.f, 0.f}};
      launch_gemm(0, false, 8192, 1024, 1024, 1024, 1024, 2048, 2, 2, z, stream);
    }
    {  // pass 2 (accumulate)
      ZP z[2] = {
        {HnIm, nullptr, MIm_b, nullptr, out,     -1.f, 1.f},
        {HnIm, nullptr, MRe_b, nullptr, out + 1,  1.f, 1.f}};
      launch_gemm(0, false, 8192, 1024, 1024, 1024, 1024, 2048, 2, 2, z, stream);
    }
  }
}

// Round 4
// 1059.970 us; speedup vs baseline: 1.1786x; 1.1593x over previous
//
#include <hip/hip_runtime.h>
#include <hip/hip_bf16.h>

#define Dd 1024
#define Bb 8192

typedef unsigned short u16;
typedef __attribute__((ext_vector_type(8))) short short8;
typedef __attribute__((ext_vector_type(4))) float f32x4;

static constexpr size_t DD  = (size_t)Dd * Dd;   // 1M
static constexpr size_t BD  = (size_t)Bb * Dd;   // 8M
static constexpr size_t MBy = 1ull << 20;

__device__ __forceinline__ float bf2f(u16 v) {
  union { unsigned u; float f; } c; c.u = ((unsigned)v) << 16; return c.f;
}
__device__ __forceinline__ u16 f2bf(float f) {
  union { float f; unsigned u; } c; c.f = f;
  return (u16)((c.u + 0x7fffu + ((c.u >> 16) & 1u)) >> 16);
}

// ---------------- NT GEMM: C[m][n] = alpha * sum_k A[m][k]*Bt[n][k] (+beta*C) ----------
// MODE 0: 1 MFMA (Ah*Bh)          — plain
// MODE 1: 3 MFMA (AhBh+AlBh+AhBl) — split-precision product
// MODE 2: 2 MFMA (AhBh+AlBl)      — pair accumulate (two independent products)
struct ZP { const u16* Ah; const u16* Al; const u16* Bh; const u16* Bl; void* C; float alpha; float beta; };
struct GArgs { ZP z[8]; int K, lda, ldb; long ldc; int cstride; };

template<int MODE, bool OBF>
__global__ __launch_bounds__(256) void gemm_nt(GArgs a) {
  constexpr bool X2 = (MODE != 0);
  __shared__ __align__(16) u16 smem[X2 ? 32768 : 16384];
  u16* As = smem;
  u16* Bs = smem + 8192;
  const ZP p = a.z[blockIdx.z];
  const int tid  = threadIdx.x;
  const int lane = tid & 63, wv = tid >> 6;

  // XCD-chunked swizzle (bijective when nwg%8==0): blocks sharing an A-row-panel
  // stay on one XCD's L2 -> A fetched once instead of x8.  [T1, m157/m204]
  int bx = blockIdx.x, by = blockIdx.y;
  {
    const int gx = gridDim.x;
    const int nwg = gx * gridDim.y;
    if ((nwg & 7) == 0 && nwg >= 16) {
      const int flat = by * gx + bx;
      const int ch = nwg >> 3;
      const int nf = (flat & 7) * ch + (flat >> 3);
      bx = nf % gx; by = nf / gx;
    }
  }

  const long brow = (long)by * 128, bcol = (long)bx * 128;
  const int wm = (wv & 1) * 64, wn = (wv >> 1) * 64;
  const int srow = wv * 8 + (lane >> 3);
  const int scol = (lane & 7) * 8;
  f32x4 acc[4][4];
#pragma unroll
  for (int i = 0; i < 4; ++i)
#pragma unroll
    for (int j = 0; j < 4; ++j) { f32x4 zv = {0.f, 0.f, 0.f, 0.f}; acc[i][j] = zv; }

  for (int kt = 0; kt < a.K; kt += 64) {
    __syncthreads();
#pragma unroll
    for (int i = 0; i < 4; ++i) {
      const int rr = i * 32 + srow;
      const int lb = (i * 32 + wv * 8) * 64;
      const u16* ga = p.Ah + (brow + rr) * (long)a.lda + kt + scol;
      const u16* gb = p.Bh + (bcol + rr) * (long)a.ldb + kt + scol;
      __builtin_amdgcn_global_load_lds((const __attribute__((address_space(1))) void*)ga,
                                       (__attribute__((address_space(3))) void*)(As + lb), 16, 0, 0);
      __builtin_amdgcn_global_load_lds((const __attribute__((address_space(1))) void*)gb,
                                       (__attribute__((address_space(3))) void*)(Bs + lb), 16, 0, 0);
      if constexpr (X2) {
        const u16* ga2 = p.Al + (brow + rr) * (long)a.lda + kt + scol;
        const u16* gb2 = p.Bl + (bcol + rr) * (long)a.ldb + kt + scol;
        __builtin_amdgcn_global_load_lds((const __attribute__((address_space(1))) void*)ga2,
                                         (__attribute__((address_space(3))) void*)(smem + 16384 + lb), 16, 0, 0);
        __builtin_amdgcn_global_load_lds((const __attribute__((address_space(1))) void*)gb2,
                                         (__attribute__((address_space(3))) void*)(smem + 24576 + lb), 16, 0, 0);
      }
    }
    __syncthreads();
#pragma unroll
    for (int kk = 0; kk < 64; kk += 32) {
      const int ko = kk + ((lane >> 4) * 8);
      short8 af[4], bfv[4], al[4], bl[4];
#pragma unroll
      for (int i = 0; i < 4; ++i) {
        af[i]  = *(const short8*)(As + (wm + i * 16 + (lane & 15)) * 64 + ko);
        bfv[i] = *(const short8*)(Bs + (wn + i * 16 + (lane & 15)) * 64 + ko);
        if constexpr (X2) {
          al[i] = *(const short8*)(smem + 16384 + (wm + i * 16 + (lane & 15)) * 64 + ko);
          bl[i] = *(const short8*)(smem + 24576 + (wn + i * 16 + (lane & 15)) * 64 + ko);
        }
      }
#pragma unroll
      for (int i = 0; i < 4; ++i)
#pragma unroll
        for (int j = 0; j < 4; ++j) {
          acc[i][j] = __builtin_amdgcn_mfma_f32_16x16x32_bf16(af[i], bfv[j], acc[i][j], 0, 0, 0);
          if constexpr (MODE == 1) {
            acc[i][j] = __builtin_amdgcn_mfma_f32_16x16x32_bf16(al[i], bfv[j], acc[i][j], 0, 0, 0);
            acc[i][j] = __builtin_amdgcn_mfma_f32_16x16x32_bf16(af[i], bl[j], acc[i][j], 0, 0, 0);
          } else if constexpr (MODE == 2) {
            acc[i][j] = __builtin_amdgcn_mfma_f32_16x16x32_bf16(al[i], bl[j], acc[i][j], 0, 0, 0);
          }
        }
    }
  }
  const long crow = brow + wm + ((lane >> 4) * 4);
  const long ccol = bcol + wn + (lane & 15);
#pragma unroll
  for (int i = 0; i < 4; ++i)
#pragma unroll
    for (int j = 0; j < 4; ++j)
#pragma unroll
      for (int r = 0; r < 4; ++r) {
        const long cidx = (crow + i * 16 + r) * a.ldc + (ccol + j * 16) * (long)a.cstride;
        float v = acc[i][j][r] * p.alpha;
        if constexpr (OBF) {
          ((u16*)p.C)[cidx] = f2bf(v);
        } else {
          float* C = (float*)p.C;
          if (p.beta != 0.0f) v += p.beta * C[cidx];
          C[cidx] = v;
        }
      }
}

// ---------------- elementwise kernels ----------------
// planes layout for complex d x d sets: [y*2*DD + 0] = re, [y*2*DD + DD] = im, y in {0(u),1(v)}

__global__ void k_buildA(const float* ur, const float* ui, const float* vr, const float* vi,
                         float* Af32, u16* Ahi, u16* Alo) {
  const int y = blockIdx.y;
  const size_t idx = (size_t)blockIdx.x * 256 + threadIdx.x;
  const size_t r = idx >> 10, c = idx & 1023;
  const float* re = y ? vr : ur; const float* im = y ? vi : ui;
  float are = 0.5f * (re[idx] - re[c * Dd + r]);
  float aim = 0.5f * (im[idx] + im[c * Dd + r]);
  size_t pr = (size_t)y * 2 * DD + idx, pi = pr + DD;
  Af32[pr] = are; Af32[pi] = aim;
  u16 h = f2bf(are); Ahi[pr] = h; Alo[pr] = f2bf(are - bf2f(h));
  h = f2bf(aim); Ahi[pi] = h; Alo[pi] = f2bf(aim - bf2f(h));
}

// X0 = I + A + A^2 ;  A^2 from 3 products/y (T3 = T2^T since Ai sym, Ar skew):
//   re = -T0-T1 ; im = T2 + T2^T
__global__ void k_x0(const float* Af32, const float* T, float* Xf32, u16* Xhi, u16* XThi) {
  const int y = blockIdx.y;
  const size_t idx = (size_t)blockIdx.x * 256 + threadIdx.x;
  const size_t r = idx >> 10, c = idx & 1023;
  const size_t t0 = (size_t)y * 3 * DD;
  float a2re = -T[t0 + idx] - T[t0 + DD + idx];
  float a2im =  T[t0 + 2 * DD + idx] + T[t0 + 2 * DD + c * Dd + r];
  size_t pr = (size_t)y * 2 * DD + idx, pi = pr + DD;
  float xre = Af32[pr] + a2re + (r == c ? 1.0f : 0.0f);
  float xim = Af32[pi] + a2im;
  Xf32[pr] = xre; Xf32[pi] = xim;
  Xhi[pr] = f2bf(xre); Xhi[pi] = f2bf(xim);
  size_t tr = c * Dd + r;
  size_t qr = (size_t)y * 2 * DD + tr;
  XThi[qr] = f2bf(xre); XThi[qr + DD] = f2bf(xim);
}

// Wt[n][k] = (idc*I - X + Q)[k][n] ; Q: re = T0-T1, im = T2+T3
// idc=2: Newton W = 2I - MX ; idc=1: refine R = I - MX
__global__ void k_wt(const float* Xf32, const float* T, u16* WThi, float idc) {
  const int y = blockIdx.y;
  const size_t idx = (size_t)blockIdx.x * 256 + threadIdx.x;  // write index: n*Dd + k
  const size_t n = idx >> 10, k = idx & 1023;
  const size_t ridx = k * Dd + n;
  const size_t t0 = (size_t)y * 4 * DD;
  float qre = T[t0 + ridx] - T[t0 + DD + ridx];
  float qim = T[t0 + 2 * DD + ridx] + T[t0 + 3 * DD + ridx];
  size_t pr = (size_t)y * 2 * DD, pi = pr + DD;
  float wre = (n == k ? idc : 0.0f) - Xf32[pr + ridx] + qre;
  float wim = -Xf32[pi + ridx] + qim;
  WThi[pr + idx] = f2bf(wre);
  WThi[pi + idx] = f2bf(wim);
}

// X' = X@W : re = T0-T1, im = T2+T3 ; optionally emit hi/lo splits (pre-refinement)
__global__ void k_xn(const float* T, float* Xf32, u16* Xhi, u16* XThi, u16* Xlo, u16* XTlo) {
  const int y = blockIdx.y;
  const size_t idx = (size_t)blockIdx.x * 256 + threadIdx.x;
  const size_t r = idx >> 10, c = idx & 1023;
  const size_t t0 = (size_t)y * 4 * DD + idx;
  float xre = T[t0] - T[t0 + DD];
  float xim = T[t0 + 2 * DD] + T[t0 + 3 * DD];
  size_t pr = (size_t)y * 2 * DD + idx, pi = pr + DD;
  Xf32[pr] = xre; Xf32[pi] = xim;
  u16 hr = f2bf(xre), hi_ = f2bf(xim);
  Xhi[pr] = hr; Xhi[pi] = hi_;
  size_t tr = (size_t)y * 2 * DD + c * Dd + r;
  XThi[tr] = hr; XThi[tr + DD] = hi_;
  if (Xlo) {
    u16 lr = f2bf(xre - bf2f(hr)), li = f2bf(xim - bf2f(hi_));
    Xlo[pr] = lr; Xlo[pi] = li;
    XTlo[tr] = lr; XTlo[tr + DD] = li;
  }
}

// Refined X_r = X + X@R (T holds X@R planes); Cay = 2*X_r - I ; emit GEMM operands
__global__ void k_finalUV(const float* Xf32, const float* T, const float* logsig,
                          u16* VsHi, u16* VsLo, u16* UHi, u16* ULo, u16* UsHi, u16* VHi) {
  const int y = blockIdx.y;
  const size_t idx = (size_t)blockIdx.x * 256 + threadIdx.x;
  const size_t r = idx >> 10, c = idx & 1023;
  const size_t t0 = (size_t)y * 4 * DD + idx;
  const size_t pr = (size_t)y * 2 * DD + idx, pi = pr + DD;
  float xre = 2.0f * (Xf32[pr] + T[t0] - T[t0 + DD]) - (r == c ? 1.0f : 0.0f);
  float xim = 2.0f * (Xf32[pi] + T[t0 + 2 * DD] + T[t0 + 3 * DD]);
  if (y == 0) {  // U:  hi/lo (Bt of M_inv) ; U*s hi (A of M)
    float s = expf(logsig[c]);
    u16 h = f2bf(xre); UHi[idx] = h; ULo[idx] = f2bf(xre - bf2f(h));
    h = f2bf(xim); UHi[DD + idx] = h; ULo[DD + idx] = f2bf(xim - bf2f(h));
    UsHi[idx] = f2bf(xre * s); UsHi[DD + idx] = f2bf(xim * s);
  } else {       // V:  hi (Bt of M) ; V*s_inv hi/lo (A of M_inv)
    float si = expf(-logsig[c]);
    VHi[idx] = f2bf(xre); VHi[DD + idx] = f2bf(xim);
    float a = xre * si, b = xim * si;
    u16 h = f2bf(a); VsHi[idx] = h; VsLo[idx] = f2bf(a - bf2f(h));
    h = f2bf(b); VsHi[DD + idx] = h; VsLo[DD + idx] = f2bf(b - bf2f(h));
  }
}

// M_inv = T0+T1, T2-T3 ; M = T4+T5, T6-T7 ; also transposed hi/lo of M_inv for G
__global__ void k_cmb_M(const float* T, u16* MiRe, u16* MiIm, u16* MiT, u16* MRe, u16* MIm) {
  const size_t idx = (size_t)blockIdx.x * 256 + threadIdx.x;
  const size_t r = idx >> 10, c = idx & 1023;
  float mire = T[idx] + T[DD + idx];
  float miim = T[2 * DD + idx] - T[3 * DD + idx];
  float mre  = T[4 * DD + idx] + T[5 * DD + idx];
  float mim  = T[6 * DD + idx] - T[7 * DD + idx];
  MiRe[idx] = f2bf(mire); MiIm[idx] = f2bf(miim);
  MRe[idx]  = f2bf(mre);  MIm[idx]  = f2bf(mim);
  size_t tr = c * Dd + r;
  u16 h = f2bf(mire); MiT[tr] = h;          MiT[2 * DD + tr] = f2bf(mire - bf2f(h));
  h = f2bf(miim);     MiT[DD + tr] = h;     MiT[3 * DD + tr] = f2bf(miim - bf2f(h));
}

__global__ void k_split(const float* src, u16* hi, u16* lo, size_t n) {
  const size_t idx = (size_t)blockIdx.x * 256 + threadIdx.x;
  if (idx >= n) return;
  float v = src[idx]; u16 h = f2bf(v); hi[idx] = h;
  if (lo) lo[idx] = f2bf(v - bf2f(h));
}

__global__ void k_pointwise(const u16* HtRe, const u16* HtIm, const u16* XtRe, const u16* XtIm,
                            const float* delta, const float* dt, const float* ld, const float* lf,
                            const float* dts, const float* sre, const float* sim,
                            const float* lwre, const float* lwim, const float* selb,
                            u16* HnRe, u16* HnIm, float imSign) {
  const size_t idx = (size_t)blockIdx.x * 256 + threadIdx.x;  // < BD
  const int b = (int)(idx >> 10); const int c = (int)(idx & 1023);
  float dre = delta[(size_t)b * 2048 + c] + selb[c];
  float dim = delta[(size_t)b * 2048 + 1024 + c] + selb[1024 + c];
  float lamre = -expf(ld[c]) + lwre[c] + dre;
  float lamim = lf[c] + lwim[c] + dim;
  float dtv = dt[b];
  float dtn = dtv / dts[c];
  float zre = lamre * dtn, zim = lamim * dtn;
  float r2 = zre * zre + zim * zim;
  float er = expf(zre); float sn, cs; __sincosf(zim, &sn, &cs);
  float dcre = er * cs, dcim = er * sn;
  float p1re, p1im;
  if (r2 < 1e-8f) {
    p1re = 1.0f + 0.5f * zre + (zre * zre - zim * zim) * (1.0f / 6.0f);
    p1im = 0.5f * zim + (zre * zim) * (1.0f / 3.0f);
  } else {
    float inv = 1.0f / r2;
    float nre = dcre - 1.0f, nim = dcim;
    p1re = (nre * zre + nim * zim) * inv;
    p1im = (nim * zre - nre * zim) * inv;
  }
  float fre = p1re * dtv, fim = p1im * dtv;  // phi1 * dt
  float hre = bf2f(HtRe[idx]), him = bf2f(HtIm[idx]);
  float xre = bf2f(XtRe[idx]) + sre[c], xim = bf2f(XtIm[idx]) + sim[c];
  float ore = hre * dcre - him * dcim + xre * fre - xim * fim;
  float oim = hre * dcim + him * dcre + xre * fim + xim * fre;
  HnRe[idx] = f2bf(ore); HnIm[idx] = f2bf(imSign * oim);
}

__global__ void k_fill(float* p, size_t n, float v) {
  const size_t idx = (size_t)blockIdx.x * 256 + threadIdx.x;
  if (idx < n) p[idx] = v;
}

// ---------------- host ----------------
static void launch_gemm(int mode, bool obf, int M, int N, int K, int lda, int ldb,
                        long ldc, int cstride, int nz, const ZP* z, hipStream_t s) {
  GArgs a; a.K = K; a.lda = lda; a.ldb = ldb; a.ldc = ldc; a.cstride = cstride;
  for (int i = 0; i < 8; ++i) a.z[i] = z[i < nz ? i : 0];
  dim3 g(N / 128, M / 128, nz), blk(256);
  if (mode == 1)      gemm_nt<1, false><<<g, blk, 0, s>>>(a);
  else if (mode == 2) gemm_nt<2, false><<<g, blk, 0, s>>>(a);
  else if (obf)       gemm_nt<0, true ><<<g, blk, 0, s>>>(a);
  else                gemm_nt<0, false><<<g, blk, 0, s>>>(a);
}

extern "C" void kernel_launch(void* const* d_in, const int* in_sizes, int n_in,
                              void* d_out, int out_size, void* d_ws, size_t ws_size,
                              hipStream_t stream) {
  const float* h_prev  = (const float*)d_in[0];
  const float* x_input = (const float*)d_in[1];
  const float* dt      = (const float*)d_in[2];
  const float* ur      = (const float*)d_in[3];
  const float* ui      = (const float*)d_in[4];
  const float* vr      = (const float*)d_in[5];
  const float* vi      = (const float*)d_in[6];
  const float* logsig  = (const float*)d_in[7];
  const float* ld      = (const float*)d_in[8];
  const float* lf      = (const float*)d_in[9];
  const float* dts     = (const float*)d_in[10];
  const float* sre     = (const float*)d_in[11];
  const float* sim     = (const float*)d_in[12];
  const float* lwre    = (const float*)d_in[13];
  const float* lwim    = (const float*)d_in[14];
  const float* sel_w   = (const float*)d_in[15];
  const float* sel_b   = (const float*)d_in[16];
  float* out = (float*)d_out;
  char* ws = (char*)d_ws;

  const bool realOnly = ((size_t)out_size == BD);
  const bool interleaved = ((size_t)out_size == 2 * BD);
  if ((!realOnly && !interleaved) || ws_size < 224 * MBy) {
    k_fill<<<dim3(((size_t)out_size + 255) / 256), dim3(256), 0, stream>>>(out, (size_t)out_size, 1e9f);
    return;
  }

  // persistent region [0,16MB)
  u16* MiRe_b = (u16*)(ws + 0 * MBy);
  u16* MiIm_b = (u16*)(ws + 2 * MBy);
  u16* MRe_b  = (u16*)(ws + 4 * MBy);
  u16* MIm_b  = (u16*)(ws + 6 * MBy);
  u16* G_hi   = (u16*)(ws + 8 * MBy);
  u16* G_lo   = (u16*)(ws + 12 * MBy);
  char* AR = ws + 16 * MBy;  // arena (phase A then reused by phase B)
  // phase A
  float* Af32 = (float*)(AR + 0);
  u16* Ahi    = (u16*)(AR + 16 * MBy);
  u16* Alo    = (u16*)(AR + 24 * MBy);
  float* Xf32 = (float*)(AR + 32 * MBy);
  u16* Xhi    = (u16*)(AR + 48 * MBy);
  u16* Xlo    = (u16*)(AR + 56 * MBy);
  u16* XThi   = (u16*)(AR + 64 * MBy);
  u16* XTlo   = (u16*)(AR + 72 * MBy);
  u16* WThi   = (u16*)(AR + 80 * MBy);
  float* T    = (float*)(AR + 96 * MBy);   // up to 8 planes f32
  u16* VsHi   = (u16*)(AR + 144 * MBy);
  u16* VsLo   = (u16*)(AR + 148 * MBy);
  u16* UHi    = (u16*)(AR + 152 * MBy);
  u16* ULo    = (u16*)(AR + 156 * MBy);
  u16* UsHi   = (u16*)(AR + 160 * MBy);
  u16* VHi    = (u16*)(AR + 164 * MBy);
  u16* MiT    = (u16*)(AR + 168 * MBy);    // ReT_hi, ImT_hi, ReT_lo, ImT_lo
  u16* W_hi   = (u16*)(AR + 176 * MBy);
  u16* W_lo   = (u16*)(AR + 184 * MBy);
  float* G_f  = (float*)(AR + 192 * MBy);
  // phase B (reuses arena)
  u16* Hb     = (u16*)(AR + 0);
  u16* XbHi   = (u16*)(AR + 16 * MBy);
  u16* XbLo   = (u16*)(AR + 32 * MBy);
  u16* HtRe   = (u16*)(AR + 48 * MBy);
  u16* HtIm   = (u16*)(AR + 64 * MBy);
  u16* XtRe   = (u16*)(AR + 80 * MBy);
  u16* XtIm   = (u16*)(AR + 96 * MBy);
  float* delta= (float*)(AR + 112 * MBy);
  u16* HnRe   = (u16*)(AR + 176 * MBy);
  u16* HnIm   = (u16*)(AR + 192 * MBy);

  dim3 b256(256);
  const dim3 gdd(4096, 2);

  // ---- Phase A: Cayley(U), Cayley(V) via Newton ----
  k_buildA<<<gdd, b256, 0, stream>>>(ur, ui, vr, vi, Af32, Ahi, Alo);

  {  // A^2: 3 products per y (T3 = T2^T by symmetry)
    ZP z[6];
    for (int y = 0; y < 2; ++y) {
      const u16* are = Ahi + (size_t)y * 2 * DD; const u16* aim = are + DD;
      float* t = T + (size_t)y * 3 * DD;
      z[y*3+0] = {are, nullptr, are, nullptr, t,          1.f, 0.f};
      z[y*3+1] = {aim, nullptr, aim, nullptr, t + DD,     1.f, 0.f};
      z[y*3+2] = {are, nullptr, aim, nullptr, t + 2*DD,   1.f, 0.f};
    }
    launch_gemm(0, false, 1024, 1024, 1024, 1024, 1024, 1024, 1, 6, z, stream);
  }
  k_x0<<<gdd, b256, 0, stream>>>(Af32, T, Xf32, Xhi, XThi);

  for (int it = 0; it < 2; ++it) {  // bf16 Newton iterations
    {  // Q = A@X
      ZP z[8];
      for (int y = 0; y < 2; ++y) {
        const u16* are = Ahi + (size_t)y*2*DD; const u16* aim = are + DD;
        const u16* xtr = XThi + (size_t)y*2*DD; const u16* xti = xtr + DD;
        float* t = T + (size_t)y*4*DD;
        z[y*4+0] = {are, nullptr, xtr, nullptr, t,        1.f, 0.f};
        z[y*4+1] = {aim, nullptr, xti, nullptr, t + DD,   1.f, 0.f};
        z[y*4+2] = {are, nullptr, xti, nullptr, t + 2*DD, 1.f, 0.f};
        z[y*4+3] = {aim, nullptr, xtr, nullptr, t + 3*DD, 1.f, 0.f};
      }
      launch_gemm(0, false, 1024, 1024, 1024, 1024, 1024, 1024, 1, 8, z, stream);
    }
    k_wt<<<gdd, b256, 0, stream>>>(Xf32, T, WThi, 2.0f);
    {  // X' = X@W
      ZP z[8];
      for (int y = 0; y < 2; ++y) {
        const u16* xre = Xhi + (size_t)y*2*DD; const u16* xim = xre + DD;
        const u16* wtr = WThi + (size_t)y*2*DD; const u16* wti = wtr + DD;
        float* t = T + (size_t)y*4*DD;
        z[y*4+0] = {xre, nullptr, wtr, nullptr, t,        1.f, 0.f};
        z[y*4+1] = {xim, nullptr, wti, nullptr, t + DD,   1.f, 0.f};
        z[y*4+2] = {xre, nullptr, wti, nullptr, t + 2*DD, 1.f, 0.f};
        z[y*4+3] = {xim, nullptr, wtr, nullptr, t + 3*DD, 1.f, 0.f};
      }
      launch_gemm(0, false, 1024, 1024, 1024, 1024, 1024, 1024, 1, 8, z, stream);
    }
    const bool last = (it == 1);
    k_xn<<<gdd, b256, 0, stream>>>(T, Xf32, Xhi, XThi,
                                   last ? Xlo : nullptr, last ? XTlo : nullptr);
  }

  {  // refine step 1: Q = A@X in split precision
    ZP z[8];
    for (int y = 0; y < 2; ++y) {
      const u16* areh = Ahi + (size_t)y*2*DD; const u16* aimh = areh + DD;
      const u16* arel = Alo + (size_t)y*2*DD; const u16* aiml = arel + DD;
      const u16* xtrh = XThi + (size_t)y*2*DD; const u16* xtih = xtrh + DD;
      const u16* xtrl = XTlo + (size_t)y*2*DD; const u16* xtil = xtrl + DD;
      float* t = T + (size_t)y*4*DD;
      z[y*4+0] = {areh, arel, xtrh, xtrl, t,        1.f, 0.f};
      z[y*4+1] = {aimh, aiml, xtih, xtil, t + DD,   1.f, 0.f};
      z[y*4+2] = {areh, arel, xtih, xtil, t + 2*DD, 1.f, 0.f};
      z[y*4+3] = {aimh, aiml, xtrh, xtrl, t + 3*DD, 1.f, 0.f};
    }
    launch_gemm(1, false, 1024, 1024, 1024, 1024, 1024, 1024, 1, 8, z, stream);
  }
  // R = I - MX (small, ~5e-3) ; then X_r = X + X@R with the product in plain bf16
  k_wt<<<gdd, b256, 0, stream>>>(Xf32, T, WThi, 1.0f);
  {  // XR = X@R (plain)
    ZP z[8];
    for (int y = 0; y < 2; ++y) {
      const u16* xre = Xhi + (size_t)y*2*DD; const u16* xim = xre + DD;
      const u16* rtr = WThi + (size_t)y*2*DD; const u16* rti = rtr + DD;
      float* t = T + (size_t)y*4*DD;
      z[y*4+0] = {xre, nullptr, rtr, nullptr, t,        1.f, 0.f};
      z[y*4+1] = {xim, nullptr, rti, nullptr, t + DD,   1.f, 0.f};
      z[y*4+2] = {xre, nullptr, rti, nullptr, t + 2*DD, 1.f, 0.f};
      z[y*4+3] = {xim, nullptr, rtr, nullptr, t + 3*DD, 1.f, 0.f};
    }
    launch_gemm(0, false, 1024, 1024, 1024, 1024, 1024, 1024, 1, 8, z, stream);
  }
  k_finalUV<<<gdd, b256, 0, stream>>>(Xf32, T, logsig, VsHi, VsLo, UHi, ULo, UsHi, VHi);

  {  // M_inv = (V s_inv) @ U^H (split)
    ZP z[4] = {
      {VsHi,      VsLo,      UHi,      ULo,      T,        1.f, 0.f},
      {VsHi + DD, VsLo + DD, UHi + DD, ULo + DD, T + DD,   1.f, 0.f},
      {VsHi + DD, VsLo + DD, UHi,      ULo,      T + 2*DD, 1.f, 0.f},
      {VsHi,      VsLo,      UHi + DD, ULo + DD, T + 3*DD, 1.f, 0.f}};
    launch_gemm(1, false, 1024, 1024, 1024, 1024, 1024, 1024, 1, 4, z, stream);
  }
  {  // M = (U s) @ V^H (plain)
    ZP z[4] = {
      {UsHi,      nullptr, VHi,      nullptr, T + 4*DD, 1.f, 0.f},
      {UsHi + DD, nullptr, VHi + DD, nullptr, T + 5*DD, 1.f, 0.f},
      {UsHi + DD, nullptr, VHi,      nullptr, T + 6*DD, 1.f, 0.f},
      {UsHi,      nullptr, VHi + DD, nullptr, T + 7*DD, 1.f, 0.f}};
    launch_gemm(0, false, 1024, 1024, 1024, 1024, 1024, 1024, 1, 4, z, stream);
  }
  k_cmb_M<<<dim3(4096), b256, 0, stream>>>(T, MiRe_b, MiIm_b, MiT, MRe_b, MIm_b);

  // G = W1 @ Re(Mi)^T + W2 @ Im(Mi)^T  (split precision)
  k_split<<<dim3(16384), b256, 0, stream>>>(sel_w, W_hi, W_lo, (size_t)2048 * 2048);
  {
    ZP z1[1] = {{W_hi, W_lo, MiT, MiT + 2*DD, G_f, 1.f, 0.f}};
    launch_gemm(1, false, 2048, 1024, 1024, 2048, 1024, 1024, 1, 1, z1, stream);
  }
  {
    ZP z1[1] = {{W_hi + 1024, W_lo + 1024, MiT + DD, MiT + 3*DD, G_f, 1.f, 1.f}};
    launch_gemm(1, false, 2048, 1024, 1024, 2048, 1024, 1024, 1, 1, z1, stream);
  }
  k_split<<<dim3(8192), b256, 0, stream>>>(G_f, G_hi, G_lo, (size_t)2048 * 1024);

  // ---- Phase B ----
  k_split<<<dim3(32768), b256, 0, stream>>>(x_input, XbHi, XbLo, BD);
  k_split<<<dim3(32768), b256, 0, stream>>>(h_prev, Hb, nullptr, BD);
  {  // encode: h_tilde / x_tilde (bf16 out)
    ZP z[4] = {
      {Hb,   nullptr, MiRe_b, nullptr, HtRe, 1.f, 0.f},
      {Hb,   nullptr, MiIm_b, nullptr, HtIm, 1.f, 0.f},
      {XbHi, nullptr, MiRe_b, nullptr, XtRe, 1.f, 0.f},
      {XbHi, nullptr, MiIm_b, nullptr, XtIm, 1.f, 0.f}};
    launch_gemm(0, true, 8192, 1024, 1024, 1024, 1024, 1024, 1, 4, z, stream);
  }
  // delta = x @ G^T: split precision ONLY for channels with dt_n up to 10
  // (cols [0,512) and [1024,1536)); plain bf16 for dt_n <= 0.1 cols.
  {  // split half
    ZP z[2] = {
      {XbHi, XbLo, G_hi,                 G_lo,                 delta,        1.f, 0.f},
      {XbHi, XbLo, G_hi + 1024 * (size_t)Dd, G_lo + 1024 * (size_t)Dd, delta + 1024, 1.f, 0.f}};
    launch_gemm(1, false, 8192, 512, 1024, 1024, 1024, 2048, 1, 2, z, stream);
  }
  {  // plain half
    ZP z[2] = {
      {XbHi, nullptr, G_hi + 512 * (size_t)Dd,  nullptr, delta + 512,  1.f, 0.f},
      {XbHi, nullptr, G_hi + 1536 * (size_t)Dd, nullptr, delta + 1536, 1.f, 0.f}};
    launch_gemm(0, false, 8192, 512, 1024, 1024, 1024, 2048, 1, 2, z, stream);
  }

  if (realOnly) {
    // fold minus into HnIm (imSign=-1); then out = HnRe@MRe^T + (-HnIm)@MIm^T in ONE dispatch
    k_pointwise<<<dim3(32768), b256, 0, stream>>>(HtRe, HtIm, XtRe, XtIm, delta, dt, ld, lf, dts,
                                                  sre, sim, lwre, lwim, sel_b, HnRe, HnIm, -1.0f);
    ZP z1[1] = {{HnRe, HnIm, MRe_b, MIm_b, out, 1.f, 0.f}};
    launch_gemm(2, false, 8192, 1024, 1024, 1024, 1024, 1024, 1, 1, z1, stream);
  } else {
    k_pointwise<<<dim3(32768), b256, 0, stream>>>(HtRe, HtIm, XtRe, XtIm, delta, dt, ld, lf, dts,
                                                  sre, sim, lwre, lwim, sel_b, HnRe, HnIm, 1.0f);
    {  // interleaved complex out, pass 1
      ZP z[2] = {
        {HnRe, nullptr, MRe_b, nullptr, out,     1.f, 0.f},
        {HnRe, nullptr, MIm_b, nullptr, out + 1, 1.f, 0.f}};
      launch_gemm(0, false, 8192, 1024, 1024, 1024, 1024, 2048, 2, 2, z, stream);
    }
    {  // pass 2 (accumulate)
      ZP z[2] = {
        {HnIm, nullptr, MIm_b, nullptr, out,     -1.f, 1.f},
        {HnIm, nullptr, MRe_b, nullptr, out + 1,  1.f, 1.f}};
      launch_gemm(0, false, 8192, 1024, 1024, 1024, 1024, 2048, 2, 2, z, stream);
    }
  }
}